// Round 4
// baseline (370.145 us; speedup 1.0000x reference)
//
#include <hip/hip_runtime.h>
#include <math.h>

// FastTensorSRHT: out[b,f] = scale * prod_d FWHT(x[b]*rad[d])[perm[d,f]]
// B=16384, D_IN=1024, DEGREE=4, D_FEATURES=4096, out f32.
//
// One block per batch row, 256 threads = 4 waves; wave w owns degree w.
// Layout: element e = m*64 + l (m = reg 0..15, l = lane 0..63).
// FWHT-1024 butterfly levels (commute, any order):
//   bits 6-9 : radix-16 in registers
//   bit 0,1  : DPP quad_perm xor1/xor2            (VALU)
//   bit 2,3,4: ds_swizzle xor4/xor8/xor16         (LDS pipe, no alloc/barrier)
//   bit 5    : v_permlane32_swap                  (VALU)
// Butterfly with lane-dependent sign: out = fma(v, s, partner), s = +-1.
// Only LDS: ybuf[4][1024] (16 KB) -> 6 blocks/CU vs previous 4.

#define D_IN_N 1024
#define D_FEAT 4096

typedef unsigned uint2v __attribute__((ext_vector_type(2)));

template <int CTRL>
__device__ __forceinline__ float dpp_xor(float x) {
  int r = __builtin_amdgcn_mov_dpp(__float_as_int(x), CTRL, 0xF, 0xF, true);
  return __int_as_float(r);
}

template <int IMM>
__device__ __forceinline__ float lds_swz(float x) {
  return __int_as_float(__builtin_amdgcn_ds_swizzle(__float_as_int(x), IMM));
}

__global__ __launch_bounds__(256, 6) void srht_kernel(
    const float* __restrict__ x,
    const float* __restrict__ rad,
    const int*  __restrict__ perms,
    const float* __restrict__ log_ls,
    const float* __restrict__ log_var,
    float* __restrict__ out)
{
  __shared__ float ybuf[4][D_IN_N];

  const int tid = threadIdx.x;
  const int w = tid >> 6;               // wave id == degree id
  const int l = tid & 63;               // lane
  const long long b = blockIdx.x;       // batch row

  // per-lane butterfly signs: s_k = (l bit k) ? -1 : +1
  const float s0 = (l & 1)  ? -1.0f : 1.0f;
  const float s1 = (l & 2)  ? -1.0f : 1.0f;
  const float s2 = (l & 4)  ? -1.0f : 1.0f;
  const float s3 = (l & 8)  ? -1.0f : 1.0f;
  const float s4 = (l & 16) ? -1.0f : 1.0f;
  const float s5 = (l & 32) ? -1.0f : 1.0f;

  // ---- load x*rad: e = m*64 + l, 16 coalesced dword loads each ----
  const float* xb = x + b * D_IN_N + l;
  const float* rb = rad + (long long)w * D_IN_N + l;
  float v[16];
#pragma unroll
  for (int m = 0; m < 16; ++m) v[m] = xb[m * 64] * rb[m * 64];

  // ---- bits 6-9: radix-16 in registers ----
#pragma unroll
  for (int h = 1; h < 16; h <<= 1) {
#pragma unroll
    for (int m = 0; m < 16; ++m) {
      if (!(m & h)) {
        float va = v[m], vb = v[m + h];
        v[m] = va + vb;
        v[m + h] = va - vb;
      }
    }
  }

  // ---- bit 0 (lane^1) and bit 1 (lane^2): DPP quad_perm ----
#pragma unroll
  for (int m = 0; m < 16; ++m) v[m] = fmaf(v[m], s0, dpp_xor<0xB1>(v[m]));
#pragma unroll
  for (int m = 0; m < 16; ++m) v[m] = fmaf(v[m], s1, dpp_xor<0x4E>(v[m]));

  // ---- bits 2,3,4: ds_swizzle xor4 / xor8 / xor16 ----
#pragma unroll
  for (int m = 0; m < 16; ++m) v[m] = fmaf(v[m], s2, lds_swz<0x101F>(v[m]));
#pragma unroll
  for (int m = 0; m < 16; ++m) v[m] = fmaf(v[m], s3, lds_swz<0x201F>(v[m]));
#pragma unroll
  for (int m = 0; m < 16; ++m) v[m] = fmaf(v[m], s4, lds_swz<0x401F>(v[m]));

  // ---- bit 5: permlane32_swap; out = fma(r.y, s5, r.x) ----
#pragma unroll
  for (int m = 0; m < 16; ++m) {
    unsigned u = __float_as_uint(v[m]);
    uint2v r = __builtin_amdgcn_permlane32_swap(u, u, false, false);
    v[m] = fmaf(__uint_as_float(r.y), s5, __uint_as_float(r.x));
  }

  // ---- write y: addr m*64+l, banks l%32 -> 2 lanes/bank (free) ----
#pragma unroll
  for (int m = 0; m < 16; ++m) ybuf[w][m * 64 + l] = v[m];
  __syncthreads();

  // ---- gather/product phase ----
  // scale: x/exp(ll) appears once per degree (linear) -> exp(-4*ll);
  // exp(lv/2); 1/sqrt(4096) = 1/64.
  const float scale = expf(0.5f * log_var[0] - 4.0f * log_ls[0]) * (1.0f / 64.0f);

  const float* __restrict__ y0 = ybuf[0];
  const float* __restrict__ y1 = ybuf[1];
  const float* __restrict__ y2 = ybuf[2];
  const float* __restrict__ y3 = ybuf[3];

  const int4* pm = reinterpret_cast<const int4*>(perms);  // [4][1024] int4
  float4* out4 = reinterpret_cast<float4*>(out + b * D_FEAT);
#pragma unroll 2
  for (int seg = 0; seg < 4; ++seg) {
    int fi = seg * 256 + tid;         // float4 index into this row's output
    int4 p0 = pm[0 * 1024 + fi];
    int4 p1 = pm[1 * 1024 + fi];
    int4 p2 = pm[2 * 1024 + fi];
    int4 p3 = pm[3 * 1024 + fi];
    float4 o;
    o.x = y0[p0.x] * y1[p1.x] * y2[p2.x] * y3[p3.x] * scale;
    o.y = y0[p0.y] * y1[p1.y] * y2[p2.y] * y3[p3.y] * scale;
    o.z = y0[p0.z] * y1[p1.z] * y2[p2.z] * y3[p3.z] * scale;
    o.w = y0[p0.w] * y1[p1.w] * y2[p2.w] * y3[p3.w] * scale;
    out4[fi] = o;
  }
}

extern "C" void kernel_launch(void* const* d_in, const int* in_sizes, int n_in,
                              void* d_out, int out_size, void* d_ws, size_t ws_size,
                              hipStream_t stream) {
  const float* x      = (const float*)d_in[0];
  const float* rad    = (const float*)d_in[1];
  const int*   perms  = (const int*)d_in[2];
  const float* lls    = (const float*)d_in[3];
  const float* lv     = (const float*)d_in[4];
  float* out          = (float*)d_out;

  const int batch = in_sizes[0] / D_IN_N;   // 16384
  srht_kernel<<<batch, 256, 0, stream>>>(x, rad, perms, lls, lv, out);
}